// Round 5
// baseline (226.649 us; speedup 1.0000x reference)
//
#include <hip/hip_runtime.h>
#include <hip/hip_bf16.h>

#define N_NODES 140000
#define N_EDGES 2240000
#define NFEAT 128
#define NHID 128
#define N_FRAMES 14
#define NODES_PER_FRAME 10000
#define FSLOTS 48          // per-frame LDS edge slots (Poisson(16); P(len>48) ~ 1e-11)

typedef __attribute__((ext_vector_type(8))) short frag_b16;
typedef __attribute__((ext_vector_type(4))) int frag_i4;
typedef __attribute__((ext_vector_type(4))) float f32x4;

__device__ __forceinline__ unsigned short f2bf(float f) {
    union { float f; unsigned int u; } v; v.f = f;
    unsigned int r = v.u + 0x7fffu + ((v.u >> 16) & 1u);   // RNE
    return (unsigned short)(r >> 16);
}
__device__ __forceinline__ int pk_bf16(float a, float b) {
    union { __hip_bfloat162 h; int i; } u;
    u.h = __float22bfloat162_rn(make_float2(a, b));        // v_cvt_pk_bf16_f32
    return u.i;
}
__device__ __forceinline__ float2 bf2x2(unsigned int u) {
    union { unsigned int u; float f; } lo, hi;
    lo.u = u << 16;
    hi.u = u & 0xffff0000u;
    return make_float2(lo.f, hi.f);
}

// ---------------------------------------------------------------------------
// Prep (merged): W^T bf16 conversion + CSR row offsets from sorted COO rows.
// ---------------------------------------------------------------------------
__global__ void prep_kernel(const float* __restrict__ W, unsigned short* __restrict__ WT,
                            const int* __restrict__ edge_row, int* __restrict__ row_ptr) {
    int e = blockIdx.x * blockDim.x + threadIdx.x;
    if (e < NFEAT * NHID) {
        int k = e >> 7, n = e & 127;
        WT[n * 128 + k] = f2bf(W[e]);
    }
    if (e < N_EDGES) {
        int r = edge_row[e];
        int prev = (e == 0) ? -1 : edge_row[e - 1];
        for (int q = prev + 1; q <= r; ++q) row_ptr[q] = e;
        if (e == N_EDGES - 1) {
            for (int q = r + 1; q <= N_NODES; ++q) row_ptr[q] = N_EDGES;
        }
    }
}

// ---------------------------------------------------------------------------
// GEMM: support_bf16 = bf16(x @ W), mfma_f32_16x16x32_bf16, operands swapped
// (A = W^T frag, B = x frag) -> each lane's 4 acc regs = 4 consecutive
// features of one node -> packed 8B stores.  (unchanged)
// ---------------------------------------------------------------------------
#define WT_STRIDE 136

__global__ __launch_bounds__(256) void gemm_kernel(
        const float* __restrict__ x, const unsigned short* __restrict__ WT,
        unsigned short* __restrict__ support) {
    __shared__ unsigned short wt_lds[128 * WT_STRIDE];

    const uint4* WTv = (const uint4*)WT;               // 2048 uint4
    for (int idx = threadIdx.x; idx < 2048; idx += 256) {
        uint4 d = WTv[idx];
        int elem = idx << 3;
        int n = elem >> 7, k = elem & 127;
        *(uint4*)&wt_lds[n * WT_STRIDE + k] = d;
    }

    int wave = threadIdx.x >> 6;
    int lane = threadIdx.x & 63;
    int m = lane & 15;
    int q = lane >> 4;

    long row0 = (long)blockIdx.x * 64 + wave * 16;

    int arow = (int)row0 + m;
    if (arow >= N_NODES) arow = N_NODES - 1;
    const float* xrow = x + (long)arow * 128 + q * 8;
    frag_b16 xa[4];
#pragma unroll
    for (int ks = 0; ks < 4; ++ks) {
        float4 lo = *(const float4*)(xrow + ks * 32);
        float4 hi = *(const float4*)(xrow + ks * 32 + 4);
        union { frag_b16 f; frag_i4 i; } u;
        u.i[0] = pk_bf16(lo.x, lo.y);
        u.i[1] = pk_bf16(lo.z, lo.w);
        u.i[2] = pk_bf16(hi.x, hi.y);
        u.i[3] = pk_bf16(hi.z, hi.w);
        xa[ks] = u.f;
    }

    __syncthreads();

    if (row0 < N_NODES) {
        f32x4 acc[8];
#pragma unroll
        for (int t = 0; t < 8; ++t) acc[t] = (f32x4){0.f, 0.f, 0.f, 0.f};

#pragma unroll
        for (int t = 0; t < 8; ++t) {
            const unsigned short* bp = &wt_lds[(t * 16 + m) * WT_STRIDE + q * 8];
#pragma unroll
            for (int ks = 0; ks < 4; ++ks) {
                frag_b16 wfrag = *(const frag_b16*)(bp + ks * 32);
                acc[t] = __builtin_amdgcn_mfma_f32_16x16x32_bf16(wfrag, xa[ks], acc[t], 0, 0, 0);
            }
        }

        long node = row0 + m;
        if (node < N_NODES) {
            unsigned short* srow = support + node * 128;
#pragma unroll
            for (int t = 0; t < 8; ++t) {
                int2 pk;
                pk.x = pk_bf16(acc[t][0], acc[t][1]);
                pk.y = pk_bf16(acc[t][2], acc[t][3]);
                *(int2*)(srow + t * 16 + q * 4) = pk;
            }
        }
    }
}

// ---------------------------------------------------------------------------
// Fused aggregation. Block = 128 thr = 2 waves = 1 output node.
// Wave w: frames [7w, 7w+6]; lane owns features {2*lane, 2*lane+1}.
// Each frame has a FIXED 48-slot LDS segment, zero-padded ({col=0,val=0}:
// fma identity, row-0 gathers stay L1-hot). Inner loop: 7-frame round-robin,
// 2 edges/frame/round, SOFTWARE-PIPELINED (round r+1's 14 gathers issue
// before round r's consumption) -> ~14-28 outstanding loads per wave.
// Edge metadata is wave-uniform -> LDS reads broadcast; frame lens via shfl.
// Per-frame summation order identical to previous rounds (absmax-stable).
// ---------------------------------------------------------------------------
__global__ __launch_bounds__(128) void agg_kernel(
        const unsigned short* __restrict__ support, const float* __restrict__ b,
        const float* __restrict__ edge_val, const int* __restrict__ edge_col,
        const int* __restrict__ row_ptr, float* __restrict__ out) {
    __shared__ int2  eBuf[2][7][FSLOTS];
    __shared__ float xch[2][64][2];

    const int i = blockIdx.x;
    const int lane = threadIdx.x & 63;
    const int w = threadIdx.x >> 6;
    const unsigned int* sup32 = (const unsigned int*)support;

    // --- per-frame CSR ranges in lanes 0..6; broadcast via shfl ---
    int a = 0, len = 0;
    if (lane < 7) {
        int n = (w * 7 + lane) * NODES_PER_FRAME + i;
        a = row_ptr[n];
        len = row_ptr[n + 1] - a;
    }
    int ml = len;
    ml = max(ml, __shfl_xor(ml, 1));
    ml = max(ml, __shfl_xor(ml, 2));
    ml = max(ml, __shfl_xor(ml, 4));
    const int maxlen = __shfl(ml, 0);                  // wave-uniform
    const bool fit = maxlen <= FSLOTS;

    // --- fill LDS: 48 slots per frame, zero-padded past len ---
    if (fit) {
#pragma unroll
        for (int f = 0; f < 7; ++f) {
            int aF = __shfl(a, f), lF = __shfl(len, f);
            if (lane < FSLOTS) {
                int2 v = make_int2(0, 0);
                if (lane < lF) {
                    v.x = edge_col[aF + lane];
                    v.y = __float_as_int(edge_val[aF + lane]);
                }
                eBuf[w][f][lane] = v;
            }
        }
    }

    const float2 bb = *(const float2*)&b[lane * 2];
    float accx[7], accy[7];
#pragma unroll
    for (int f = 0; f < 7; ++f) { accx[f] = 0.f; accy[f] = 0.f; }

    if (fit) {
        const int R = (maxlen + 1) >> 1;               // rounds of 2 edges/frame
        int4 cur[7];
        unsigned sv0[7], sv1[7];

        // prologue: round 0 metadata + gathers
#pragma unroll
        for (int f = 0; f < 7; ++f) cur[f] = *(const int4*)&eBuf[w][f][0];
#pragma unroll
        for (int f = 0; f < 7; ++f) {
            sv0[f] = sup32[((unsigned)cur[f].x << 6) | lane];
            sv1[f] = sup32[((unsigned)cur[f].z << 6) | lane];
        }

#pragma unroll 1
        for (int r = 0; r < R; ++r) {
            int ro = (r + 1) * 2;
            if (ro > FSLOTS - 2) ro = FSLOTS - 2;      // clamp (last prefetch unused)
            int4 nxt[7];
            unsigned nv0[7], nv1[7];
#pragma unroll
            for (int f = 0; f < 7; ++f) nxt[f] = *(const int4*)&eBuf[w][f][ro];
#pragma unroll
            for (int f = 0; f < 7; ++f) {
                nv0[f] = sup32[((unsigned)nxt[f].x << 6) | lane];
                nv1[f] = sup32[((unsigned)nxt[f].z << 6) | lane];
            }
            // consume current round (pads: val=0 -> exact identity)
#pragma unroll
            for (int f = 0; f < 7; ++f) {
                float v0 = __int_as_float(cur[f].y);
                float v1 = __int_as_float(cur[f].w);
                float2 s0 = bf2x2(sv0[f]);
                float2 s1 = bf2x2(sv1[f]);
                accx[f] = fmaf(v0, s0.x, accx[f]);
                accy[f] = fmaf(v0, s0.y, accy[f]);
                accx[f] = fmaf(v1, s1.x, accx[f]);
                accy[f] = fmaf(v1, s1.y, accy[f]);
            }
#pragma unroll
            for (int f = 0; f < 7; ++f) {
                cur[f] = nxt[f];
                sv0[f] = nv0[f];
                sv1[f] = nv1[f];
            }
        }
    } else {
        // safety fallback: direct global reads (identical per-frame order)
#pragma unroll 1
        for (int f = 0; f < 7; ++f) {
            int aF = __shfl(a, f), lF = __shfl(len, f);
            float ax = 0.f, ay = 0.f;
            for (int j = 0; j < lF; ++j) {
                int c = edge_col[aF + j];
                float v = edge_val[aF + j];
                float2 s2 = bf2x2(sup32[((unsigned)c << 6) | lane]);
                ax = fmaf(v, s2.x, ax);
                ay = fmaf(v, s2.y, ay);
            }
            accx[f] = ax; accy[f] = ay;
        }
    }

    // --- relu + bias + max over this wave's 7 frames ---
    float2 mx = make_float2(0.f, 0.f);                 // relu => max >= 0
#pragma unroll
    for (int f = 0; f < 7; ++f) {
        float hx = accx[f] + bb.x, hy = accy[f] + bb.y;
        mx.x = fmaxf(mx.x, hx > 0.f ? hx : 0.f);
        mx.y = fmaxf(mx.y, hy > 0.f ? hy : 0.f);
    }

    // --- cross-wave max exchange ---
    xch[w][lane][0] = mx.x;
    xch[w][lane][1] = mx.y;
    __syncthreads();
    float ox = fmaxf(xch[0][lane][0], xch[1][lane][0]);
    float oy = fmaxf(xch[0][lane][1], xch[1][lane][1]);

    // --- in-wave log_softmax over 128 features ---
    float M = fmaxf(ox, oy);
#pragma unroll
    for (int o = 32; o >= 1; o >>= 1) M = fmaxf(M, __shfl_xor(M, o));
    float S = __expf(ox - M) + __expf(oy - M);
#pragma unroll
    for (int o = 32; o >= 1; o >>= 1) S += __shfl_xor(S, o);

    if (w == 0) {
        float ls = __logf(S);
        float2 o2 = make_float2((ox - M) - ls, (oy - M) - ls);
        *(float2*)&out[i * 128 + lane * 2] = o2;
    }
}

// ---------------------------------------------------------------------------
extern "C" void kernel_launch(void* const* d_in, const int* in_sizes, int n_in,
                              void* d_out, int out_size, void* d_ws, size_t ws_size,
                              hipStream_t stream) {
    const float* x        = (const float*)d_in[0];
    const float* W        = (const float*)d_in[1];
    const float* b        = (const float*)d_in[2];
    const float* edge_val = (const float*)d_in[3];
    const int*   edge_row = (const int*)d_in[4];
    const int*   edge_col = (const int*)d_in[5];
    float* out = (float*)d_out;

    char* ws = (char*)d_ws;
    unsigned short* support = (unsigned short*)ws;                  // 35,840,000 B
    unsigned short* WT      = (unsigned short*)(ws + 35840000);     //     32,768 B
    int*            row_ptr = (int*)(ws + 35840000 + 32768);        //    560,004 B

    prep_kernel<<<(N_EDGES + 255) / 256, 256, 0, stream>>>(W, WT, edge_row, row_ptr);
    gemm_kernel<<<(N_NODES + 63) / 64, 256, 0, stream>>>(x, WT, support);
    agg_kernel<<<NODES_PER_FRAME, 128, 0, stream>>>(support, b, edge_val, edge_col, row_ptr, out);
}

// Round 6
// 198.671 us; speedup vs baseline: 1.1408x; 1.1408x over previous
//
#include <hip/hip_runtime.h>
#include <hip/hip_bf16.h>

#define N_NODES 140000
#define N_EDGES 2240000
#define NFEAT 128
#define NHID 128
#define N_FRAMES 14
#define NODES_PER_FRAME 10000
#define CAP 352            // int2 LDS slots per wave (7 frames padded to x8)

typedef __attribute__((ext_vector_type(8))) short frag_b16;
typedef __attribute__((ext_vector_type(4))) int frag_i4;
typedef __attribute__((ext_vector_type(4))) float f32x4;

__device__ __forceinline__ unsigned short f2bf(float f) {
    union { float f; unsigned int u; } v; v.f = f;
    unsigned int r = v.u + 0x7fffu + ((v.u >> 16) & 1u);   // RNE
    return (unsigned short)(r >> 16);
}
__device__ __forceinline__ int pk_bf16(float a, float b) {
    union { __hip_bfloat162 h; int i; } u;
    u.h = __float22bfloat162_rn(make_float2(a, b));        // v_cvt_pk_bf16_f32
    return u.i;
}

// ---------------------------------------------------------------------------
// Prep (merged): W^T bf16 conversion + CSR row offsets from sorted COO rows.
// ---------------------------------------------------------------------------
__global__ void prep_kernel(const float* __restrict__ W, unsigned short* __restrict__ WT,
                            const int* __restrict__ edge_row, int* __restrict__ row_ptr) {
    int e = blockIdx.x * blockDim.x + threadIdx.x;
    if (e < NFEAT * NHID) {
        int k = e >> 7, n = e & 127;
        WT[n * 128 + k] = f2bf(W[e]);
    }
    if (e < N_EDGES) {
        int r = edge_row[e];
        int prev = (e == 0) ? -1 : edge_row[e - 1];
        for (int q = prev + 1; q <= r; ++q) row_ptr[q] = e;
        if (e == N_EDGES - 1) {
            for (int q = r + 1; q <= N_NODES; ++q) row_ptr[q] = N_EDGES;
        }
    }
}

// ---------------------------------------------------------------------------
// GEMM: support = x @ W via mfma_f32_16x16x32_bf16 (operands swapped so each
// lane's 4 acc regs = 4 consecutive features of one node). NEW epilogue:
// quantize each node row to u8 (biased int8) with per-row scale:
//   u = rint(S * 127/rowmax) + 128,  scales[node] = rowmax/127
// Row = 128 B -> ONE L2 line per downstream gather (was 2 with bf16).
// ---------------------------------------------------------------------------
#define WT_STRIDE 136

__global__ __launch_bounds__(256) void gemm_kernel(
        const float* __restrict__ x, const unsigned short* __restrict__ WT,
        unsigned char* __restrict__ supQ, float* __restrict__ scales) {
    __shared__ unsigned short wt_lds[128 * WT_STRIDE];

    const uint4* WTv = (const uint4*)WT;               // 2048 uint4
    for (int idx = threadIdx.x; idx < 2048; idx += 256) {
        uint4 d = WTv[idx];
        int elem = idx << 3;
        int n = elem >> 7, k = elem & 127;
        *(uint4*)&wt_lds[n * WT_STRIDE + k] = d;
    }

    int wave = threadIdx.x >> 6;
    int lane = threadIdx.x & 63;
    int m = lane & 15;
    int q = lane >> 4;

    long row0 = (long)blockIdx.x * 64 + wave * 16;

    int arow = (int)row0 + m;
    if (arow >= N_NODES) arow = N_NODES - 1;
    const float* xrow = x + (long)arow * 128 + q * 8;
    frag_b16 xa[4];
#pragma unroll
    for (int ks = 0; ks < 4; ++ks) {
        float4 lo = *(const float4*)(xrow + ks * 32);
        float4 hi = *(const float4*)(xrow + ks * 32 + 4);
        union { frag_b16 f; frag_i4 i; } u;
        u.i[0] = pk_bf16(lo.x, lo.y);
        u.i[1] = pk_bf16(lo.z, lo.w);
        u.i[2] = pk_bf16(hi.x, hi.y);
        u.i[3] = pk_bf16(hi.z, hi.w);
        xa[ks] = u.f;
    }

    __syncthreads();

    if (row0 < N_NODES) {
        f32x4 acc[8];
#pragma unroll
        for (int t = 0; t < 8; ++t) acc[t] = (f32x4){0.f, 0.f, 0.f, 0.f};

#pragma unroll
        for (int t = 0; t < 8; ++t) {
            const unsigned short* bp = &wt_lds[(t * 16 + m) * WT_STRIDE + q * 8];
#pragma unroll
            for (int ks = 0; ks < 4; ++ks) {
                frag_b16 wfrag = *(const frag_b16*)(bp + ks * 32);
                acc[t] = __builtin_amdgcn_mfma_f32_16x16x32_bf16(wfrag, xa[ks], acc[t], 0, 0, 0);
            }
        }

        // --- int8 row quantization epilogue ---
        float amax = 0.f;
#pragma unroll
        for (int t = 0; t < 8; ++t)
#pragma unroll
            for (int r = 0; r < 4; ++r) amax = fmaxf(amax, fabsf(acc[t][r]));
        // lanes (m, q=0..3) hold one node's 128 feats: reduce over q (xor 16,32)
        amax = fmaxf(amax, __shfl_xor(amax, 16));
        amax = fmaxf(amax, __shfl_xor(amax, 32));
        float rinv = amax > 0.f ? 127.f / amax : 0.f;

        long node = row0 + m;
        if (node < N_NODES) {
            if (q == 0) scales[node] = amax * (1.f / 127.f);
            unsigned char* srow = supQ + node * 128;
#pragma unroll
            for (int t = 0; t < 8; ++t) {
                unsigned u0 = (unsigned)(rintf(acc[t][0] * rinv) + 128.f);
                unsigned u1 = (unsigned)(rintf(acc[t][1] * rinv) + 128.f);
                unsigned u2 = (unsigned)(rintf(acc[t][2] * rinv) + 128.f);
                unsigned u3 = (unsigned)(rintf(acc[t][3] * rinv) + 128.f);
                *(unsigned*)(srow + t * 16 + q * 4) = u0 | (u1 << 8) | (u2 << 16) | (u3 << 24);
            }
        }
    }
}

// ---------------------------------------------------------------------------
// Fused aggregation v3. Block = 128 thr = 2 waves = 1 output node.
// Wave w: frames [7w, 7w+6]. Lane = (eh = lane>>5: edge-of-pair,
// f4 = lane&31: feature quad) -> one dword gather = 4 features, 2 edges per
// wave-instruction, ONE 128B line per edge row (int8 table).
// Decode: u8 -> float via ubyte cvt; msg = val' * u - 128*val'
// with val' = edge_val * scales[col] folded at LDS staging time; the -128
// correction is one fma per frame (svf = per-frame sum of val').
// Per-frame halves reduced via shfl_xor(32); staging padded-to-8 with
// {col=0, val'=0} (exact fma identity, row-0 pads stay cache-hot).
// ---------------------------------------------------------------------------
__global__ __launch_bounds__(128) void agg_kernel(
        const unsigned char* __restrict__ supQ, const float* __restrict__ scales,
        const float* __restrict__ b,
        const float* __restrict__ edge_val, const int* __restrict__ edge_col,
        const int* __restrict__ row_ptr, float* __restrict__ out) {
    __shared__ int    segStart[2][8];
    __shared__ int    segLen[2][8];
    __shared__ int    segOff[2][8];
    __shared__ int2   eBuf[2][CAP];
    __shared__ float4 xch[2][32];

    const int i = blockIdx.x;
    const int lane = threadIdx.x & 63;
    const int w = threadIdx.x >> 6;
    const int eh = lane >> 5;                          // which edge of a pair
    const int f4 = lane & 31;                          // feature quad
    const unsigned f4x4 = (unsigned)f4 * 4u;

    // --- CSR ranges in lanes 0..6; padded-to-8 exclusive scan ---
    int a = 0, len = 0;
    if (lane < 7) {
        int n = (w * 7 + lane) * NODES_PER_FRAME + i;
        a = row_ptr[n];
        len = row_ptr[n + 1] - a;
    }
    int len8 = (len + 7) & ~7;
    int off = 0;
#pragma unroll
    for (int f2 = 0; f2 < 7; ++f2) {
        int L2 = __shfl(len8, f2);
        if (f2 < lane) off += L2;
    }
    if (lane < 7) { segStart[w][lane] = a; segLen[w][lane] = len; segOff[w][lane] = off; }
    if (lane == 6) segOff[w][7] = off + len8;
    __syncthreads();

    const bool fit = segOff[w][7] <= CAP;              // wave-uniform

    // --- stage (col, val'=val*scale[col]) into LDS, zero-padded per frame ---
    if (fit) {
#pragma unroll 1
        for (int f = 0; f < 7; ++f) {
            int g = segStart[w][f], s = segOff[w][f], L = segLen[w][f];
            int L8 = (L + 7) & ~7;
            for (int j = lane; j < L8; j += 64) {
                int2 v = make_int2(0, 0);
                if (j < L) {
                    int c = edge_col[g + j];
                    v.x = c;
                    v.y = __float_as_int(edge_val[g + j] * scales[c]);
                }
                eBuf[w][s + j] = v;
            }
        }
    }
    __syncthreads();

    const float4 bb = *(const float4*)&b[f4 * 4];
    float4 mx = make_float4(0.f, 0.f, 0.f, 0.f);       // relu => max >= 0

    if (fit) {
#pragma unroll 1
        for (int f = 0; f < 7; ++f) {
            int s = segOff[w][f];
            int e8 = s + ((segLen[w][f] + 7) & ~7);
            float a0 = 0.f, a1 = 0.f, a2 = 0.f, a3 = 0.f, svf = 0.f;
            for (int j = s; j < e8; j += 8) {
                int2 ed[4];
#pragma unroll
                for (int p = 0; p < 4; ++p) ed[p] = eBuf[w][j + 2 * p + eh];
                unsigned q4[4];
#pragma unroll
                for (int p = 0; p < 4; ++p)
                    q4[p] = *(const unsigned*)(supQ + (((unsigned)ed[p].x) << 7) + f4x4);
#pragma unroll
                for (int p = 0; p < 4; ++p) {
                    float vp = __int_as_float(ed[p].y);
                    a0 = fmaf(vp, (float)( q4[p]        & 0xffu), a0);
                    a1 = fmaf(vp, (float)((q4[p] >> 8)  & 0xffu), a1);
                    a2 = fmaf(vp, (float)((q4[p] >> 16) & 0xffu), a2);
                    a3 = fmaf(vp, (float)( q4[p] >> 24        ), a3);
                    svf += vp;
                }
            }
            a0 += __shfl_xor(a0, 32); a1 += __shfl_xor(a1, 32);
            a2 += __shfl_xor(a2, 32); a3 += __shfl_xor(a3, 32);
            svf += __shfl_xor(svf, 32);
            float h0 = fmaf(-128.f, svf, a0) + bb.x;
            float h1 = fmaf(-128.f, svf, a1) + bb.y;
            float h2 = fmaf(-128.f, svf, a2) + bb.z;
            float h3 = fmaf(-128.f, svf, a3) + bb.w;
            mx.x = fmaxf(mx.x, fmaxf(h0, 0.f));
            mx.y = fmaxf(mx.y, fmaxf(h1, 0.f));
            mx.z = fmaxf(mx.z, fmaxf(h2, 0.f));
            mx.w = fmaxf(mx.w, fmaxf(h3, 0.f));
        }
    } else {
        // safety fallback: direct global reads, same math, halves split by eh
#pragma unroll 1
        for (int f = 0; f < 7; ++f) {
            int g = segStart[w][f], L = segLen[w][f];
            float a0 = 0.f, a1 = 0.f, a2 = 0.f, a3 = 0.f, svf = 0.f;
            for (int j = eh; j < L; j += 2) {
                int c = edge_col[g + j];
                float vp = edge_val[g + j] * scales[c];
                unsigned qv = *(const unsigned*)(supQ + (((unsigned)c) << 7) + f4x4);
                a0 = fmaf(vp, (float)( qv        & 0xffu), a0);
                a1 = fmaf(vp, (float)((qv >> 8)  & 0xffu), a1);
                a2 = fmaf(vp, (float)((qv >> 16) & 0xffu), a2);
                a3 = fmaf(vp, (float)( qv >> 24        ), a3);
                svf += vp;
            }
            a0 += __shfl_xor(a0, 32); a1 += __shfl_xor(a1, 32);
            a2 += __shfl_xor(a2, 32); a3 += __shfl_xor(a3, 32);
            svf += __shfl_xor(svf, 32);
            float h0 = fmaf(-128.f, svf, a0) + bb.x;
            float h1 = fmaf(-128.f, svf, a1) + bb.y;
            float h2 = fmaf(-128.f, svf, a2) + bb.z;
            float h3 = fmaf(-128.f, svf, a3) + bb.w;
            mx.x = fmaxf(mx.x, fmaxf(h0, 0.f));
            mx.y = fmaxf(mx.y, fmaxf(h1, 0.f));
            mx.z = fmaxf(mx.z, fmaxf(h2, 0.f));
            mx.w = fmaxf(mx.w, fmaxf(h3, 0.f));
        }
    }

    // --- cross-wave max exchange (halves are identical post-reduction) ---
    if (eh == 0) xch[w][f4] = mx;
    __syncthreads();
    float4 m0 = xch[0][f4], m1 = xch[1][f4];
    float o0 = fmaxf(m0.x, m1.x);
    float o1 = fmaxf(m0.y, m1.y);
    float o2 = fmaxf(m0.z, m1.z);
    float o3 = fmaxf(m0.w, m1.w);

    // --- log_softmax over 128 feats (reduce across the 32 f4 groups) ---
    float M = fmaxf(fmaxf(o0, o1), fmaxf(o2, o3));
#pragma unroll
    for (int o = 16; o >= 1; o >>= 1) M = fmaxf(M, __shfl_xor(M, o));
    float S = __expf(o0 - M) + __expf(o1 - M) + __expf(o2 - M) + __expf(o3 - M);
#pragma unroll
    for (int o = 16; o >= 1; o >>= 1) S += __shfl_xor(S, o);

    if (w == 0 && eh == 0) {
        float ls = __logf(S);
        *(float4*)&out[i * 128 + f4 * 4] =
            make_float4(o0 - M - ls, o1 - M - ls, o2 - M - ls, o3 - M - ls);
    }
}

// ---------------------------------------------------------------------------
extern "C" void kernel_launch(void* const* d_in, const int* in_sizes, int n_in,
                              void* d_out, int out_size, void* d_ws, size_t ws_size,
                              hipStream_t stream) {
    const float* x        = (const float*)d_in[0];
    const float* W        = (const float*)d_in[1];
    const float* b        = (const float*)d_in[2];
    const float* edge_val = (const float*)d_in[3];
    const int*   edge_row = (const int*)d_in[4];
    const int*   edge_col = (const int*)d_in[5];
    float* out = (float*)d_out;

    char* ws = (char*)d_ws;
    unsigned char*  supQ    = (unsigned char*)ws;                   // 17,920,000 B
    float*          scales  = (float*)(ws + 17920000);              //    560,000 B
    unsigned short* WT      = (unsigned short*)(ws + 18480000);     //     32,768 B
    int*            row_ptr = (int*)(ws + 18512768);                //    560,004 B

    prep_kernel<<<(N_EDGES + 255) / 256, 256, 0, stream>>>(W, WT, edge_row, row_ptr);
    gemm_kernel<<<(N_NODES + 63) / 64, 256, 0, stream>>>(x, WT, supQ, scales);
    agg_kernel<<<NODES_PER_FRAME, 128, 0, stream>>>(supQ, scales, b, edge_val, edge_col, row_ptr, out);
}